// Round 21
// baseline (240.032 us; speedup 1.0000x reference)
//
#include <hip/hip_runtime.h>
#include <stdint.h>

#define AS1 __attribute__((address_space(1)))
#define AS3 __attribute__((address_space(3)))

typedef __bf16 bf16x8 __attribute__((ext_vector_type(8)));
typedef float  f32x4  __attribute__((ext_vector_type(4)));

static constexpr int NODES  = 50000;
static constexpr int EDGES  = 800000;
static constexpr int INDIM  = 512;
static constexpr int HIDDIM = 256;
static constexpr int NB_SCAN = (NODES + 255) / 256;   // 196
static constexpr int AGG_BLOCKS = 2048;               // persistent grid-stride (both aggs)
static constexpr int RED_BLOCKS = 64;
static constexpr int GEMM_MB256 = (NODES + 255) / 256; // 196 row-blocks (BM=256)

// ---------------- ws layout (bytes) ----------------
static constexpr size_t OFF_PART = 0;            // f32  [2048][256] (2 MB)
static constexpr size_t OFF_HN   = 51200000;     // fp8  [50000][256] pre-scaled h (both layers)
static constexpr size_t OFF_H1P  = 76800000;     // fp8  [50000][256] relu(layer1) output
static constexpr size_t OFF_W1T  = 102400000;    // bf16 [256][512]
static constexpr size_t OFF_W2T8 = 102662144;    // fp8  [256][256]
static constexpr size_t OFF_DEG  = 102793216;    // i32 [50000]
static constexpr size_t OFF_FILL = 102993216;    // i32 [50000]
static constexpr size_t OFF_ROWP = 103193216;    // i32 [50001]
static constexpr size_t OFF_CSR  = 103393280;    // i32 [800000]
static constexpr size_t OFF_BSUM = 106593280;    // i32 [196]
static constexpr size_t OFF_BOFF = 106594304;    // i32 [256]
static constexpr size_t OFF_P2   = 106595840;    // f32 [64][256]
static constexpr size_t OFF_DINV = 106661376;    // f32 [50000]

__device__ __forceinline__ unsigned short f2bf(float f) {
  unsigned u = __builtin_bit_cast(unsigned, f);
  unsigned r = (u + 0x7FFFu + ((u >> 16) & 1u)) >> 16;   // RNE
  return (unsigned short)r;
}
__device__ __forceinline__ unsigned char f2fp8(float f) {
  int p = __builtin_amdgcn_cvt_pk_fp8_f32(f, f, 0, false);   // OCP e4m3fn
  return (unsigned char)(p & 0xff);
}
__device__ __forceinline__ void acc_fp8(float4& a, unsigned u) {
  a.x += __builtin_amdgcn_cvt_f32_fp8(u, 0);
  a.y += __builtin_amdgcn_cvt_f32_fp8(u, 1);
  a.z += __builtin_amdgcn_cvt_f32_fp8(u, 2);
  a.w += __builtin_amdgcn_cvt_f32_fp8(u, 3);
}
__device__ __forceinline__ void gload_lds16(const void* g, void* l) {
  __builtin_amdgcn_global_load_lds((const AS1 void*)g, (AS3 void*)l, 16, 0, 0);
}

// counted-wait primitives (T4)
#define WAITVM(N)  asm volatile("s_waitcnt vmcnt(" #N ")" ::: "memory")
#define WAITLGKM   asm volatile("s_waitcnt lgkmcnt(0)" ::: "memory")
#define HWBARRIER  { asm volatile("" ::: "memory"); __builtin_amdgcn_s_barrier(); \
                     asm volatile("" ::: "memory"); }

// ---- LDS-bounce epilogue (R19, confirmed -10.5us) ----
#define BOUNCE_EPILOGUE                                                       \
  {                                                                           \
    char* Lb = SMEM;                                                          \
    const int rq = q * 4;                                                     \
    _Pragma("unroll")                                                         \
    for (int m = 0; m < 8; ++m) {                                             \
      _Pragma("unroll")                                                       \
      for (int r = 0; r < 4; ++r) {                                           \
        int rt = wr * 128 + m * 16 + rq + r;                                  \
        int grow = m0 + rt;                                                   \
        if (grow < NODES) {                                                   \
          float dv = dinv[grow];                                              \
          _Pragma("unroll")                                                   \
          for (int n = 0; n < 4; ++n) {                                       \
            int ch = (wc * 4 + n) ^ (rt & 15);                                \
            Lb[rt * 256 + ch * 16 + fr] = (char)f2fp8(acc[m][n][r] * dv);     \
          }                                                                   \
        }                                                                     \
      }                                                                       \
    }                                                                         \
    HWBARRIER;                                                                \
    _Pragma("unroll")                                                         \
    for (int p = 0; p < 8; ++p) {                                             \
      int idx = p * 512 + tid;              /* 0..4095: (row, 16B seg) */     \
      int rt = idx >> 4, seg = idx & 15;                                      \
      int grow = m0 + rt;                                                     \
      if (grow < NODES)                                                       \
        *(uint4*)(Cn8 + (size_t)grow * 256 + seg * 16) =                      \
            *(const uint4*)(Lb + rt * 256 + ((seg ^ (rt & 15)) * 16));        \
    }                                                                         \
  }

// -------- weight prep: W1T bf16, W2T fp8 + scratch zeroing (fused) --------
__global__ __launch_bounds__(256) void transw_zero_kernel(const float* __restrict__ W1,
                                                          const float* __restrict__ W2,
                                                          unsigned short* __restrict__ W1T,
                                                          unsigned char* __restrict__ W2T8,
                                                          int4* __restrict__ zreg) {
  int b = blockIdx.x, tid = threadIdx.x;
  if (b < 512) {                                    // W1T[n][k] = bf16(W1[k][n])
    int t = b * 256 + tid; int n = t >> 9, k = t & 511;
    W1T[t] = f2bf(W1[k * HIDDIM + n]);
  } else if (b < 768) {                             // W2T8[n][k] = fp8(W2[k][n])
    int u = (b - 512) * 256 + tid; int n = u >> 8, k = u & 255;
    W2T8[u] = f2fp8(W2[k * HIDDIM + n]);
  } else {                                          // zero deg+fill (400000 B)
    int i = (b - 768) * 256 + tid;
    if (i < 25000) zreg[i] = int4{0, 0, 0, 0};
  }
}

// ---------------- degree histogram (inline int64-layout detect) ----------------
__global__ __launch_bounds__(256) void hist_kernel(const int* __restrict__ ei,
                                                   int* __restrict__ deg) {
  __shared__ int sflag;
  if (threadIdx.x < 64) {
    unsigned long long b = __ballot(ei[2 * threadIdx.x + 1] == 0);
    if (threadIdx.x == 0) sflag = (b == 0xFFFFFFFFFFFFFFFFull) ? 1 : 0;
  }
  __syncthreads();
  int f = sflag;
  int e = blockIdx.x * 256 + threadIdx.x;        // 3125*256 = 800000 exact
  int d = f ? ei[2 * (EDGES + e)] : ei[EDGES + e];
  atomicAdd(&deg[d], 1);
}

// ---------------- scan (3 kernels) + dinv ----------------
__global__ __launch_bounds__(256) void scan1_kernel(const int* __restrict__ deg,
                                                    int* __restrict__ rowptr,
                                                    int* __restrict__ bsum,
                                                    float* __restrict__ dinv) {
  __shared__ int s[256];
  int t = threadIdx.x, i = blockIdx.x * 256 + t;
  int v = (i < NODES) ? deg[i] : 0;
  if (i < NODES) dinv[i] = rsqrtf((float)(v + 1));   // +1 self-loop
  s[t] = v; __syncthreads();
  for (int off = 1; off < 256; off <<= 1) {
    int x = (t >= off) ? s[t - off] : 0;
    __syncthreads(); s[t] += x; __syncthreads();
  }
  if (i < NODES) rowptr[i] = s[t] - v;
  if (t == 255) bsum[blockIdx.x] = s[255];
}
__global__ __launch_bounds__(256) void scan2_kernel(const int* __restrict__ bsum,
                                                    int* __restrict__ boff,
                                                    int* __restrict__ rowptrN) {
  __shared__ int s[256];
  int t = threadIdx.x;
  int v = (t < NB_SCAN) ? bsum[t] : 0;
  s[t] = v; __syncthreads();
  for (int off = 1; off < 256; off <<= 1) {
    int x = (t >= off) ? s[t - off] : 0;
    __syncthreads(); s[t] += x; __syncthreads();
  }
  if (t < NB_SCAN) boff[t] = s[t] - v;
  if (t == 255) *rowptrN = s[255];
}
__global__ __launch_bounds__(256) void scan3_kernel(int* __restrict__ rowptr,
                                                    const int* __restrict__ boff) {
  int i = blockIdx.x * 256 + threadIdx.x;
  if (i < NODES) rowptr[i] += boff[blockIdx.x];
}

// ---------------- CSR fill (inline detect) ----------------
__global__ __launch_bounds__(256) void fill_kernel(const int* __restrict__ ei,
                                                   const int* __restrict__ rowptr,
                                                   int* __restrict__ fill,
                                                   int* __restrict__ csr) {
  __shared__ int sflag;
  if (threadIdx.x < 64) {
    unsigned long long b = __ballot(ei[2 * threadIdx.x + 1] == 0);
    if (threadIdx.x == 0) sflag = (b == 0xFFFFFFFFFFFFFFFFull) ? 1 : 0;
  }
  __syncthreads();
  int f = sflag;
  int e = blockIdx.x * 256 + threadIdx.x;
  int s, d;
  if (f) { s = ei[2 * e]; d = ei[2 * (EDGES + e)]; }
  else   { s = ei[e];     d = ei[EDGES + e]; }
  int p = atomicAdd(&fill[d], 1);
  csr[rowptr[d] + p] = s;
}

// ------- GEMM1: BM=BN=256, BK=32, counted vmcnt, bf16 MFMA, bounce epilogue -------
__global__ __launch_bounds__(512, 2) void gemm1_kernel(const float* __restrict__ A,
                                                       const unsigned short* __restrict__ BT,
                                                       const float* __restrict__ dinv,
                                                       unsigned char* __restrict__ Cn8) {
  constexpr int K = INDIM, NSTEP = K / 32;
  __shared__ char SMEM[65536];
  unsigned short (*As)[8192] = (unsigned short (*)[8192])SMEM;          // 2x16KB
  unsigned short (*Bs)[8192] = (unsigned short (*)[8192])(SMEM + 32768);// 2x16KB
  const int tid = threadIdx.x, wave = tid >> 6, lane = tid & 63;
  const int fr = lane & 15, q = lane >> 4;
  const int wr = wave >> 2, wc = wave & 3;     // 2m x 4n
  const int m0 = blockIdx.x * 256;

  const int lrow4 = lane >> 2;                 // 0..15: row within 16-row slab
  const int sgq   = (lane & 3) ^ (lrow4 & 3);  // pre-swizzled source 16B group

  f32x4 acc[8][4] = {};
  float4 fa[4];                                // fp32 A staging regs

#define STAGE_B(buf, kb)                                                      \
  {                                                                           \
    _Pragma("unroll")                                                         \
    for (int c = 0; c < 2; ++c) {                                             \
      int rbase = wave * 32 + c * 16;                                         \
      int gr = rbase + lrow4;                                                 \
      gload_lds16(BT + (size_t)gr * K + (kb) + sgq * 8, &Bs[buf][rbase * 32]);\
    }                                                                         \
  }
#define LOAD_A32(kb)                                                          \
  {                                                                           \
    _Pragma("unroll")                                                         \
    for (int j = 0; j < 4; ++j) {                                             \
      int F = tid + j * 512;                                                  \
      int r0 = m0 + (F >> 3); if (r0 > NODES - 1) r0 = NODES - 1;             \
      fa[j] = *(const float4*)(A + (size_t)r0 * K + (kb) + (F & 7) * 4);      \
    }                                                                         \
  }
#define WRITE_A32(buf)                                                        \
  {                                                                           \
    _Pragma("unroll")                                                         \
    for (int j = 0; j < 4; ++j) {                                             \
      int F = tid + j * 512;                                                  \
      int row = F >> 3, g4 = F & 7;                                           \
      ushort4 o{f2bf(fa[j].x), f2bf(fa[j].y), f2bf(fa[j].z), f2bf(fa[j].w)};  \
      int col = (((g4 >> 1) ^ (row & 3)) * 8) + (g4 & 1) * 4;                 \
      *(ushort4*)&As[buf][row * 32 + col] = o;                                \
    }                                                                         \
  }

  LOAD_A32(0); WRITE_A32(0); WAITLGKM;
  STAGE_B(0, 0);

  for (int t = 0; t < NSTEP; ++t) {
    const int cur = t & 1, nxt = cur ^ 1;
    if (t + 1 < NSTEP) {
      const int kb1 = (t + 1) * 32;
      LOAD_A32(kb1);
      STAGE_B(nxt, kb1);
      WAITVM(6);
    } else {
      WAITVM(0);
    }
    HWBARRIER;

    bf16x8 af[8], bq[4];
#pragma unroll
    for (int m = 0; m < 8; ++m) {
      int row = wr * 128 + m * 16 + fr;
      af[m] = *(const bf16x8*)&As[cur][row * 32 + ((q ^ (row & 3)) * 8)];
    }
#pragma unroll
    for (int n = 0; n < 4; ++n) {
      int row = wc * 64 + n * 16 + fr;
      bq[n] = *(const bf16x8*)&Bs[cur][row * 32 + ((q ^ (row & 3)) * 8)];
    }
#pragma unroll
    for (int m = 0; m < 8; ++m)
#pragma unroll
      for (int n = 0; n < 4; ++n)
        acc[m][n] = __builtin_amdgcn_mfma_f32_16x16x32_bf16(af[m], bq[n], acc[m][n], 0, 0, 0);

    if (t + 1 < NSTEP) { WRITE_A32(nxt); WAITLGKM; }
    HWBARRIER;
  }
#undef STAGE_B
#undef LOAD_A32
#undef WRITE_A32

  BOUNCE_EPILOGUE;
}

// ------- GEMM2: fp8 memory + native fp8 MFMA, BK=64, bounce epilogue -------
__global__ __launch_bounds__(512, 2) void gemm2_fp8_kernel(const unsigned char* __restrict__ A8,
                                                           const unsigned char* __restrict__ BT8,
                                                           const float* __restrict__ dinv,
                                                           unsigned char* __restrict__ Cn8) {
  constexpr int K = HIDDIM, NSTEP = K / 64;    // 4
  __shared__ char SMEM[65536];
  unsigned char (*As)[16384] = (unsigned char (*)[16384])SMEM;           // 2x16KB
  unsigned char (*Bs)[16384] = (unsigned char (*)[16384])(SMEM + 32768); // 2x16KB
  const int tid = threadIdx.x, wave = tid >> 6, lane = tid & 63;
  const int fr = lane & 15, q = lane >> 4;
  const int wr = wave >> 2, wc = wave & 3;     // 2m x 4n
  const int m0 = blockIdx.x * 256;

  const int srl0 = lane >> 2, sch = lane & 3;  // staging: (row lane>>2, 16B grp lane&3)

  f32x4 acc[8][4] = {};

#define STAGE_T(dstArr, buf, srcp, rowbase, kb, CLAMP)                        \
  {                                                                           \
    _Pragma("unroll")                                                         \
    for (int c = 0; c < 2; ++c) {                                             \
      int rl = (wave * 2 + c) * 16 + srl0;                                    \
      int gr = (rowbase) + rl;                                                \
      if (CLAMP) { if (gr > NODES - 1) gr = NODES - 1; }                      \
      const unsigned char* sp = srcp + (size_t)gr * K + (kb) +                \
                                ((sch ^ (rl & 3)) << 4);                      \
      gload_lds16(sp, &dstArr[buf][(wave * 2 + c) * 1024]);                   \
    }                                                                         \
  }

  STAGE_T(As, 0, A8, m0, 0, true);
  STAGE_T(Bs, 0, BT8, 0, 0, false);

  for (int t = 0; t < NSTEP; ++t) {
    const int cur = t & 1, nxt = cur ^ 1;
    if (t + 1 < NSTEP) {
      const int kb1 = (t + 1) * 64;
      STAGE_T(As, nxt, A8, m0, kb1, true);
      STAGE_T(Bs, nxt, BT8, 0, kb1, false);
      WAITVM(4);
    } else {
      WAITVM(0);
    }
    HWBARRIER;

#pragma unroll
    for (int s = 0; s < 2; ++s) {               // two K=32 slabs per step
      long af[8], bq[4];
#pragma unroll
      for (int m = 0; m < 8; ++m) {
        int row = wr * 128 + m * 16 + fr;
        int cch = s * 2 + (q >> 1);
        af[m] = *(const long*)
            &As[cur][row * 64 + ((cch ^ (row & 3)) << 4) + (q & 1) * 8];
      }
#pragma unroll
      for (int n = 0; n < 4; ++n) {
        int row = wc * 64 + n * 16 + fr;
        int cch = s * 2 + (q >> 1);
        bq[n] = *(const long*)
            &Bs[cur][row * 64 + ((cch ^ (row & 3)) << 4) + (q & 1) * 8];
      }
#pragma unroll
      for (int m = 0; m < 8; ++m)
#pragma unroll
        for (int n = 0; n < 4; ++n)
          acc[m][n] = __builtin_amdgcn_mfma_f32_16x16x32_fp8_fp8(af[m], bq[n], acc[m][n], 0, 0, 0);
    }
    HWBARRIER;
  }
#undef STAGE_T

  BOUNCE_EPILOGUE;
}

// --- gather core: SGPR-uniform csr indices, unroll-16/8/4/scalar (R18) ---
__device__ __forceinline__ float4 gather_node(const unsigned char* __restrict__ hn8,
                                              const int* __restrict__ rowptr,
                                              const int* __restrict__ csr,
                                              int node, int boff) {
  float4 A{0.f, 0.f, 0.f, 0.f}, B{0.f, 0.f, 0.f, 0.f};
  acc_fp8(A, *(const unsigned*)(hn8 + (size_t)node * 256 + boff));   // self-loop
  int e0  = __builtin_amdgcn_readfirstlane(rowptr[node]);
  int cnt = __builtin_amdgcn_readfirstlane(rowptr[node + 1]) - e0;
  const int* cp = csr + e0;
  int i = 0;
  for (; i + 16 <= cnt; i += 16) {
    unsigned v[16];
#pragma unroll
    for (int j = 0; j < 16; ++j)
      v[j] = *(const unsigned*)(hn8 + (size_t)cp[i + j] * 256 + boff);
#pragma unroll
    for (int j = 0; j < 16; j += 2) { acc_fp8(A, v[j]); acc_fp8(B, v[j + 1]); }
  }
  for (; i + 8 <= cnt; i += 8) {
    unsigned v[8];
#pragma unroll
    for (int j = 0; j < 8; ++j)
      v[j] = *(const unsigned*)(hn8 + (size_t)cp[i + j] * 256 + boff);
#pragma unroll
    for (int j = 0; j < 8; j += 2) { acc_fp8(A, v[j]); acc_fp8(B, v[j + 1]); }
  }
  for (; i + 4 <= cnt; i += 4) {
    unsigned v[4];
#pragma unroll
    for (int j = 0; j < 4; ++j)
      v[j] = *(const unsigned*)(hn8 + (size_t)cp[i + j] * 256 + boff);
    acc_fp8(A, v[0]); acc_fp8(B, v[1]); acc_fp8(A, v[2]); acc_fp8(B, v[3]);
  }
  for (; i < cnt; ++i)
    acc_fp8(A, *(const unsigned*)(hn8 + (size_t)cp[i] * 256 + boff));
  return float4{A.x + B.x, A.y + B.y, A.z + B.z, A.w + B.w};
}

// ------- agg1: persistent grid-stride (2048 blocks), per-node fp8 output -------
__global__ __launch_bounds__(256) void agg1_kernel(const unsigned char* __restrict__ hn8,
                                                   const float* __restrict__ dinv,
                                                   const int* __restrict__ rowptr,
                                                   const int* __restrict__ csr,
                                                   const float* __restrict__ bias,
                                                   unsigned char* __restrict__ h1p8) {
  int wave = threadIdx.x >> 6, lane = threadIdx.x & 63;
  int c0 = lane * 4;
  float4 b = *(const float4*)(bias + c0);
  for (int node = blockIdx.x * 4 + wave; node < NODES; node += AGG_BLOCKS * 4) {
    float4 a = gather_node(hn8, rowptr, csr, node, c0);
    float di = dinv[node];
    float r0 = fmaxf(fmaf(di, a.x, b.x), 0.f);
    float r1 = fmaxf(fmaf(di, a.y, b.y), 0.f);
    float r2 = fmaxf(fmaf(di, a.z, b.z), 0.f);
    float r3 = fmaxf(fmaf(di, a.w, b.w), 0.f);
    int p = __builtin_amdgcn_cvt_pk_fp8_f32(r0, r1, 0, false);
    p     = __builtin_amdgcn_cvt_pk_fp8_f32(r2, r3, p, true);
    *(unsigned*)(h1p8 + (size_t)node * 256 + c0) = (unsigned)p;
  }
}

// ------- agg2: persistent grid-stride, register accumulation (R20, confirmed) -------
__global__ __launch_bounds__(256) void agg2_kernel(const unsigned char* __restrict__ hn8,
                                                   const float* __restrict__ dinv,
                                                   const int* __restrict__ rowptr,
                                                   const int* __restrict__ csr,
                                                   const float* __restrict__ bias,
                                                   float* __restrict__ partials) {
  __shared__ float sm[1024];
  int wave = threadIdx.x >> 6, lane = threadIdx.x & 63;
  int c0 = lane * 4;
  float4 bq = *(const float4*)(bias + c0);
  float s0 = 0.f, s1 = 0.f, s2 = 0.f, s3 = 0.f;
  for (int node = blockIdx.x * 4 + wave; node < NODES; node += AGG_BLOCKS * 4) {
    float4 a = gather_node(hn8, rowptr, csr, node, c0);
    float di = dinv[node];
    s0 += fmaxf(fmaf(di, a.x, bq.x), 0.f);
    s1 += fmaxf(fmaf(di, a.y, bq.y), 0.f);
    s2 += fmaxf(fmaf(di, a.z, bq.z), 0.f);
    s3 += fmaxf(fmaf(di, a.w, bq.w), 0.f);
  }
  sm[wave * 256 + c0 + 0] = s0;
  sm[wave * 256 + c0 + 1] = s1;
  sm[wave * 256 + c0 + 2] = s2;
  sm[wave * 256 + c0 + 3] = s3;
  __syncthreads();
  int t = threadIdx.x;
  partials[(size_t)blockIdx.x * 256 + t] = sm[t] + sm[256 + t] + sm[512 + t] + sm[768 + t];
}

// ---------------- readout ----------------
__global__ __launch_bounds__(256) void reduce2_kernel(const float* __restrict__ partials,
                                                      float* __restrict__ p2) {
  int t = threadIdx.x, b = blockIdx.x;              // 64 blocks
  float s = 0.f;
  for (int r = b; r < AGG_BLOCKS; r += RED_BLOCKS) s += partials[(size_t)r * 256 + t];
  p2[b * 256 + t] = s;
}
__global__ __launch_bounds__(256) void final_kernel(const float* __restrict__ p2,
                                                    const float* __restrict__ Wfc,
                                                    const float* __restrict__ bfc,
                                                    float* __restrict__ out) {
  __shared__ float red[256];
  int t = threadIdx.x;
  float s = 0.f;
  for (int b = 0; b < RED_BLOCKS; ++b) s += p2[b * 256 + t];
  float g = s * (1.0f / (float)NODES);
  red[t] = g * Wfc[t];
  __syncthreads();
  for (int off = 128; off > 0; off >>= 1) {
    if (t < off) red[t] += red[t + off];
    __syncthreads();
  }
  if (t == 0) {
    float z = red[0] + bfc[0];
    out[0] = 1.0f / (1.0f + expf(-z));
  }
}

// ---------------- launch ----------------
extern "C" void kernel_launch(void* const* d_in, const int* in_sizes, int n_in,
                              void* d_out, int out_size, void* d_ws, size_t ws_size,
                              hipStream_t stream) {
  (void)in_sizes; (void)n_in; (void)out_size; (void)ws_size;
  const float* x   = (const float*)d_in[0];
  const int*   ei  = (const int*)d_in[1];
  const float* W1  = (const float*)d_in[2];
  const float* b1  = (const float*)d_in[3];
  const float* W2  = (const float*)d_in[4];
  const float* b2  = (const float*)d_in[5];
  const float* Wfc = (const float*)d_in[6];
  const float* bfc = (const float*)d_in[7];
  float* out = (float*)d_out;
  char* ws = (char*)d_ws;

  unsigned char*  hn8  = (unsigned char*)(ws + OFF_HN);
  unsigned char*  h1p8 = (unsigned char*)(ws + OFF_H1P);
  unsigned short* w1t  = (unsigned short*)(ws + OFF_W1T);
  unsigned char*  w2t8 = (unsigned char*)(ws + OFF_W2T8);
  int*   deg    = (int*)(ws + OFF_DEG);
  int*   fill   = (int*)(ws + OFF_FILL);
  int*   rowptr = (int*)(ws + OFF_ROWP);
  int*   csr    = (int*)(ws + OFF_CSR);
  int*   bsum   = (int*)(ws + OFF_BSUM);
  int*   boff   = (int*)(ws + OFF_BOFF);
  float* part   = (float*)(ws + OFF_PART);
  float* p2     = (float*)(ws + OFF_P2);
  float* dinv   = (float*)(ws + OFF_DINV);

  transw_zero_kernel<<<866, 256, 0, stream>>>(W1, W2, w1t, w2t8, (int4*)deg);
  hist_kernel<<<EDGES / 256, 256, 0, stream>>>(ei, deg);
  scan1_kernel<<<NB_SCAN, 256, 0, stream>>>(deg, rowptr, bsum, dinv);
  scan2_kernel<<<1, 256, 0, stream>>>(bsum, boff, rowptr + NODES);
  scan3_kernel<<<NB_SCAN, 256, 0, stream>>>(rowptr, boff);
  fill_kernel<<<EDGES / 256, 256, 0, stream>>>(ei, rowptr, fill, csr);

  gemm1_kernel<<<GEMM_MB256, 512, 0, stream>>>(x, w1t, dinv, hn8);
  agg1_kernel<<<AGG_BLOCKS, 256, 0, stream>>>(hn8, dinv, rowptr, csr, b1, h1p8);
  gemm2_fp8_kernel<<<GEMM_MB256, 512, 0, stream>>>(h1p8, w2t8, dinv, hn8);
  agg2_kernel<<<AGG_BLOCKS, 256, 0, stream>>>(hn8, dinv, rowptr, csr, b2, part);
  reduce2_kernel<<<RED_BLOCKS, 256, 0, stream>>>(part, p2);
  final_kernel<<<1, 256, 0, stream>>>(p2, Wfc, bfc, out);
}

// Round 22
// 223.543 us; speedup vs baseline: 1.0738x; 1.0738x over previous
//
#include <hip/hip_runtime.h>
#include <stdint.h>

#define AS1 __attribute__((address_space(1)))
#define AS3 __attribute__((address_space(3)))

typedef __bf16 bf16x8 __attribute__((ext_vector_type(8)));
typedef float  f32x4  __attribute__((ext_vector_type(4)));

static constexpr int NODES  = 50000;
static constexpr int EDGES  = 800000;
static constexpr int INDIM  = 512;
static constexpr int HIDDIM = 256;
static constexpr int NB_SCAN = (NODES + 255) / 256;   // 196
static constexpr int AGG_BLOCKS = NODES / 4;          // 12500 (agg1)
static constexpr int AGG2_BLOCKS = 2048;              // grid-stride agg2
static constexpr int RED_BLOCKS = 64;
static constexpr int GEMM_MB256 = (NODES + 255) / 256; // 196 row-blocks (BM=256)

// ---------------- ws layout (bytes) ----------------
static constexpr size_t OFF_PART = 0;            // f32  [2048][256] (2 MB)
static constexpr size_t OFF_HN   = 51200000;     // fp8  [50000][256] pre-scaled h (both layers)
static constexpr size_t OFF_H1P  = 76800000;     // fp8  [50000][256] relu(layer1) output
static constexpr size_t OFF_W1T  = 102400000;    // bf16 [256][512]
static constexpr size_t OFF_W2T8 = 102662144;    // fp8  [256][256]
static constexpr size_t OFF_DEG  = 102793216;    // i32 [50000]
static constexpr size_t OFF_FILL = 102993216;    // i32 [50000]
static constexpr size_t OFF_ROWP = 103193216;    // i32 [50001]
static constexpr size_t OFF_CSR  = 103393280;    // i32 [800000]
static constexpr size_t OFF_BSUM = 106593280;    // i32 [196]
static constexpr size_t OFF_BOFF = 106594304;    // i32 [256]
static constexpr size_t OFF_P2   = 106595840;    // f32 [64][256]
static constexpr size_t OFF_DINV = 106661376;    // f32 [50000]

__device__ __forceinline__ unsigned short f2bf(float f) {
  unsigned u = __builtin_bit_cast(unsigned, f);
  unsigned r = (u + 0x7FFFu + ((u >> 16) & 1u)) >> 16;   // RNE
  return (unsigned short)r;
}
__device__ __forceinline__ unsigned char f2fp8(float f) {
  int p = __builtin_amdgcn_cvt_pk_fp8_f32(f, f, 0, false);   // OCP e4m3fn
  return (unsigned char)(p & 0xff);
}
__device__ __forceinline__ void acc_fp8(float4& a, unsigned u) {
  a.x += __builtin_amdgcn_cvt_f32_fp8(u, 0);
  a.y += __builtin_amdgcn_cvt_f32_fp8(u, 1);
  a.z += __builtin_amdgcn_cvt_f32_fp8(u, 2);
  a.w += __builtin_amdgcn_cvt_f32_fp8(u, 3);
}
__device__ __forceinline__ void gload_lds16(const void* g, void* l) {
  __builtin_amdgcn_global_load_lds((const AS1 void*)g, (AS3 void*)l, 16, 0, 0);
}

// counted-wait primitives (T4)
#define WAITVM(N)  asm volatile("s_waitcnt vmcnt(" #N ")" ::: "memory")
#define WAITLGKM   asm volatile("s_waitcnt lgkmcnt(0)" ::: "memory")
#define HWBARRIER  { asm volatile("" ::: "memory"); __builtin_amdgcn_s_barrier(); \
                     asm volatile("" ::: "memory"); }

// ---- LDS-bounce epilogue (R19, confirmed -10.5us): byte-writes to swizzled
// LDS, barrier, coalesced dwordx4 global stores ----
#define BOUNCE_EPILOGUE                                                       \
  {                                                                           \
    char* Lb = SMEM;                                                          \
    const int rq = q * 4;                                                     \
    _Pragma("unroll")                                                         \
    for (int m = 0; m < 8; ++m) {                                             \
      _Pragma("unroll")                                                       \
      for (int r = 0; r < 4; ++r) {                                           \
        int rt = wr * 128 + m * 16 + rq + r;                                  \
        int grow = m0 + rt;                                                   \
        if (grow < NODES) {                                                   \
          float dv = dinv[grow];                                              \
          _Pragma("unroll")                                                   \
          for (int n = 0; n < 4; ++n) {                                       \
            int ch = (wc * 4 + n) ^ (rt & 15);                                \
            Lb[rt * 256 + ch * 16 + fr] = (char)f2fp8(acc[m][n][r] * dv);     \
          }                                                                   \
        }                                                                     \
      }                                                                       \
    }                                                                         \
    HWBARRIER;                                                                \
    _Pragma("unroll")                                                         \
    for (int p = 0; p < 8; ++p) {                                             \
      int idx = p * 512 + tid;              /* 0..4095: (row, 16B seg) */     \
      int rt = idx >> 4, seg = idx & 15;                                      \
      int grow = m0 + rt;                                                     \
      if (grow < NODES)                                                       \
        *(uint4*)(Cn8 + (size_t)grow * 256 + seg * 16) =                      \
            *(const uint4*)(Lb + rt * 256 + ((seg ^ (rt & 15)) * 16));        \
    }                                                                         \
  }

// -------- weight prep: W1T bf16, W2T fp8 + scratch zeroing (fused) --------
__global__ __launch_bounds__(256) void transw_zero_kernel(const float* __restrict__ W1,
                                                          const float* __restrict__ W2,
                                                          unsigned short* __restrict__ W1T,
                                                          unsigned char* __restrict__ W2T8,
                                                          int4* __restrict__ zreg) {
  int b = blockIdx.x, tid = threadIdx.x;
  if (b < 512) {                                    // W1T[n][k] = bf16(W1[k][n])
    int t = b * 256 + tid; int n = t >> 9, k = t & 511;
    W1T[t] = f2bf(W1[k * HIDDIM + n]);
  } else if (b < 768) {                             // W2T8[n][k] = fp8(W2[k][n])
    int u = (b - 512) * 256 + tid; int n = u >> 8, k = u & 255;
    W2T8[u] = f2fp8(W2[k * HIDDIM + n]);
  } else {                                          // zero deg+fill (400000 B)
    int i = (b - 768) * 256 + tid;
    if (i < 25000) zreg[i] = int4{0, 0, 0, 0};
  }
}

// ---------------- degree histogram (inline int64-layout detect) ----------------
__global__ __launch_bounds__(256) void hist_kernel(const int* __restrict__ ei,
                                                   int* __restrict__ deg) {
  __shared__ int sflag;
  if (threadIdx.x < 64) {
    unsigned long long b = __ballot(ei[2 * threadIdx.x + 1] == 0);
    if (threadIdx.x == 0) sflag = (b == 0xFFFFFFFFFFFFFFFFull) ? 1 : 0;
  }
  __syncthreads();
  int f = sflag;
  int e = blockIdx.x * 256 + threadIdx.x;        // 3125*256 = 800000 exact
  int d = f ? ei[2 * (EDGES + e)] : ei[EDGES + e];
  atomicAdd(&deg[d], 1);
}

// ---------------- scan (3 kernels) + dinv ----------------
__global__ __launch_bounds__(256) void scan1_kernel(const int* __restrict__ deg,
                                                    int* __restrict__ rowptr,
                                                    int* __restrict__ bsum,
                                                    float* __restrict__ dinv) {
  __shared__ int s[256];
  int t = threadIdx.x, i = blockIdx.x * 256 + t;
  int v = (i < NODES) ? deg[i] : 0;
  if (i < NODES) dinv[i] = rsqrtf((float)(v + 1));   // +1 self-loop
  s[t] = v; __syncthreads();
  for (int off = 1; off < 256; off <<= 1) {
    int x = (t >= off) ? s[t - off] : 0;
    __syncthreads(); s[t] += x; __syncthreads();
  }
  if (i < NODES) rowptr[i] = s[t] - v;
  if (t == 255) bsum[blockIdx.x] = s[255];
}
__global__ __launch_bounds__(256) void scan2_kernel(const int* __restrict__ bsum,
                                                    int* __restrict__ boff,
                                                    int* __restrict__ rowptrN) {
  __shared__ int s[256];
  int t = threadIdx.x;
  int v = (t < NB_SCAN) ? bsum[t] : 0;
  s[t] = v; __syncthreads();
  for (int off = 1; off < 256; off <<= 1) {
    int x = (t >= off) ? s[t - off] : 0;
    __syncthreads(); s[t] += x; __syncthreads();
  }
  if (t < NB_SCAN) boff[t] = s[t] - v;
  if (t == 255) *rowptrN = s[255];
}
__global__ __launch_bounds__(256) void scan3_kernel(int* __restrict__ rowptr,
                                                    const int* __restrict__ boff) {
  int i = blockIdx.x * 256 + threadIdx.x;
  if (i < NODES) rowptr[i] += boff[blockIdx.x];
}

// ---------------- CSR fill (inline detect) ----------------
__global__ __launch_bounds__(256) void fill_kernel(const int* __restrict__ ei,
                                                   const int* __restrict__ rowptr,
                                                   int* __restrict__ fill,
                                                   int* __restrict__ csr) {
  __shared__ int sflag;
  if (threadIdx.x < 64) {
    unsigned long long b = __ballot(ei[2 * threadIdx.x + 1] == 0);
    if (threadIdx.x == 0) sflag = (b == 0xFFFFFFFFFFFFFFFFull) ? 1 : 0;
  }
  __syncthreads();
  int f = sflag;
  int e = blockIdx.x * 256 + threadIdx.x;
  int s, d;
  if (f) { s = ei[2 * e]; d = ei[2 * (EDGES + e)]; }
  else   { s = ei[e];     d = ei[EDGES + e]; }
  int p = atomicAdd(&fill[d], 1);
  csr[rowptr[d] + p] = s;
}

// ------- GEMM1: BM=BN=256, BK=32, counted vmcnt, bf16 MFMA, bounce epilogue -------
__global__ __launch_bounds__(512, 2) void gemm1_kernel(const float* __restrict__ A,
                                                       const unsigned short* __restrict__ BT,
                                                       const float* __restrict__ dinv,
                                                       unsigned char* __restrict__ Cn8) {
  constexpr int K = INDIM, NSTEP = K / 32;
  __shared__ char SMEM[65536];
  unsigned short (*As)[8192] = (unsigned short (*)[8192])SMEM;          // 2x16KB
  unsigned short (*Bs)[8192] = (unsigned short (*)[8192])(SMEM + 32768);// 2x16KB
  const int tid = threadIdx.x, wave = tid >> 6, lane = tid & 63;
  const int fr = lane & 15, q = lane >> 4;
  const int wr = wave >> 2, wc = wave & 3;     // 2m x 4n
  const int m0 = blockIdx.x * 256;

  const int lrow4 = lane >> 2;                 // 0..15: row within 16-row slab
  const int sgq   = (lane & 3) ^ (lrow4 & 3);  // pre-swizzled source 16B group

  f32x4 acc[8][4] = {};
  float4 fa[4];                                // fp32 A staging regs

#define STAGE_B(buf, kb)                                                      \
  {                                                                           \
    _Pragma("unroll")                                                         \
    for (int c = 0; c < 2; ++c) {                                             \
      int rbase = wave * 32 + c * 16;                                         \
      int gr = rbase + lrow4;                                                 \
      gload_lds16(BT + (size_t)gr * K + (kb) + sgq * 8, &Bs[buf][rbase * 32]);\
    }                                                                         \
  }
#define LOAD_A32(kb)                                                          \
  {                                                                           \
    _Pragma("unroll")                                                         \
    for (int j = 0; j < 4; ++j) {                                             \
      int F = tid + j * 512;                                                  \
      int r0 = m0 + (F >> 3); if (r0 > NODES - 1) r0 = NODES - 1;             \
      fa[j] = *(const float4*)(A + (size_t)r0 * K + (kb) + (F & 7) * 4);      \
    }                                                                         \
  }
#define WRITE_A32(buf)                                                        \
  {                                                                           \
    _Pragma("unroll")                                                         \
    for (int j = 0; j < 4; ++j) {                                             \
      int F = tid + j * 512;                                                  \
      int row = F >> 3, g4 = F & 7;                                           \
      ushort4 o{f2bf(fa[j].x), f2bf(fa[j].y), f2bf(fa[j].z), f2bf(fa[j].w)};  \
      int col = (((g4 >> 1) ^ (row & 3)) * 8) + (g4 & 1) * 4;                 \
      *(ushort4*)&As[buf][row * 32 + col] = o;                                \
    }                                                                         \
  }

  LOAD_A32(0); WRITE_A32(0); WAITLGKM;
  STAGE_B(0, 0);

  for (int t = 0; t < NSTEP; ++t) {
    const int cur = t & 1, nxt = cur ^ 1;
    if (t + 1 < NSTEP) {
      const int kb1 = (t + 1) * 32;
      LOAD_A32(kb1);
      STAGE_B(nxt, kb1);
      WAITVM(6);
    } else {
      WAITVM(0);
    }
    HWBARRIER;

    bf16x8 af[8], bq[4];
#pragma unroll
    for (int m = 0; m < 8; ++m) {
      int row = wr * 128 + m * 16 + fr;
      af[m] = *(const bf16x8*)&As[cur][row * 32 + ((q ^ (row & 3)) * 8)];
    }
#pragma unroll
    for (int n = 0; n < 4; ++n) {
      int row = wc * 64 + n * 16 + fr;
      bq[n] = *(const bf16x8*)&Bs[cur][row * 32 + ((q ^ (row & 3)) * 8)];
    }
#pragma unroll
    for (int m = 0; m < 8; ++m)
#pragma unroll
      for (int n = 0; n < 4; ++n)
        acc[m][n] = __builtin_amdgcn_mfma_f32_16x16x32_bf16(af[m], bq[n], acc[m][n], 0, 0, 0);

    if (t + 1 < NSTEP) { WRITE_A32(nxt); WAITLGKM; }
    HWBARRIER;
  }
#undef STAGE_B
#undef LOAD_A32
#undef WRITE_A32

  BOUNCE_EPILOGUE;
}

// ------- GEMM2: fp8 memory + native fp8 MFMA, BK=64, bounce epilogue -------
__global__ __launch_bounds__(512, 2) void gemm2_fp8_kernel(const unsigned char* __restrict__ A8,
                                                           const unsigned char* __restrict__ BT8,
                                                           const float* __restrict__ dinv,
                                                           unsigned char* __restrict__ Cn8) {
  constexpr int K = HIDDIM, NSTEP = K / 64;    // 4
  __shared__ char SMEM[65536];
  unsigned char (*As)[16384] = (unsigned char (*)[16384])SMEM;           // 2x16KB
  unsigned char (*Bs)[16384] = (unsigned char (*)[16384])(SMEM + 32768); // 2x16KB
  const int tid = threadIdx.x, wave = tid >> 6, lane = tid & 63;
  const int fr = lane & 15, q = lane >> 4;
  const int wr = wave >> 2, wc = wave & 3;     // 2m x 4n
  const int m0 = blockIdx.x * 256;

  const int srl0 = lane >> 2, sch = lane & 3;  // staging: (row lane>>2, 16B grp lane&3)

  f32x4 acc[8][4] = {};

#define STAGE_T(dstArr, buf, srcp, rowbase, kb, CLAMP)                        \
  {                                                                           \
    _Pragma("unroll")                                                         \
    for (int c = 0; c < 2; ++c) {                                             \
      int rl = (wave * 2 + c) * 16 + srl0;                                    \
      int gr = (rowbase) + rl;                                                \
      if (CLAMP) { if (gr > NODES - 1) gr = NODES - 1; }                      \
      const unsigned char* sp = srcp + (size_t)gr * K + (kb) +                \
                                ((sch ^ (rl & 3)) << 4);                      \
      gload_lds16(sp, &dstArr[buf][(wave * 2 + c) * 1024]);                   \
    }                                                                         \
  }

  STAGE_T(As, 0, A8, m0, 0, true);
  STAGE_T(Bs, 0, BT8, 0, 0, false);

  for (int t = 0; t < NSTEP; ++t) {
    const int cur = t & 1, nxt = cur ^ 1;
    if (t + 1 < NSTEP) {
      const int kb1 = (t + 1) * 64;
      STAGE_T(As, nxt, A8, m0, kb1, true);
      STAGE_T(Bs, nxt, BT8, 0, kb1, false);
      WAITVM(4);
    } else {
      WAITVM(0);
    }
    HWBARRIER;

#pragma unroll
    for (int s = 0; s < 2; ++s) {               // two K=32 slabs per step
      long af[8], bq[4];
#pragma unroll
      for (int m = 0; m < 8; ++m) {
        int row = wr * 128 + m * 16 + fr;
        int cch = s * 2 + (q >> 1);
        af[m] = *(const long*)
            &As[cur][row * 64 + ((cch ^ (row & 3)) << 4) + (q & 1) * 8];
      }
#pragma unroll
      for (int n = 0; n < 4; ++n) {
        int row = wc * 64 + n * 16 + fr;
        int cch = s * 2 + (q >> 1);
        bq[n] = *(const long*)
            &Bs[cur][row * 64 + ((cch ^ (row & 3)) << 4) + (q & 1) * 8];
      }
#pragma unroll
      for (int m = 0; m < 8; ++m)
#pragma unroll
        for (int n = 0; n < 4; ++n)
          acc[m][n] = __builtin_amdgcn_mfma_f32_16x16x32_fp8_fp8(af[m], bq[n], acc[m][n], 0, 0, 0);
    }
    HWBARRIER;
  }
#undef STAGE_T

  BOUNCE_EPILOGUE;
}

// --- gather core: SGPR-uniform csr indices, unroll-16/8/4/scalar (R18) ---
__device__ __forceinline__ float4 gather_node(const unsigned char* __restrict__ hn8,
                                              const int* __restrict__ rowptr,
                                              const int* __restrict__ csr,
                                              int node, int boff) {
  float4 A{0.f, 0.f, 0.f, 0.f}, B{0.f, 0.f, 0.f, 0.f};
  acc_fp8(A, *(const unsigned*)(hn8 + (size_t)node * 256 + boff));   // self-loop
  int e0  = __builtin_amdgcn_readfirstlane(rowptr[node]);
  int cnt = __builtin_amdgcn_readfirstlane(rowptr[node + 1]) - e0;
  const int* cp = csr + e0;
  int i = 0;
  for (; i + 16 <= cnt; i += 16) {
    unsigned v[16];
#pragma unroll
    for (int j = 0; j < 16; ++j)
      v[j] = *(const unsigned*)(hn8 + (size_t)cp[i + j] * 256 + boff);
#pragma unroll
    for (int j = 0; j < 16; j += 2) { acc_fp8(A, v[j]); acc_fp8(B, v[j + 1]); }
  }
  for (; i + 8 <= cnt; i += 8) {
    unsigned v[8];
#pragma unroll
    for (int j = 0; j < 8; ++j)
      v[j] = *(const unsigned*)(hn8 + (size_t)cp[i + j] * 256 + boff);
#pragma unroll
    for (int j = 0; j < 8; j += 2) { acc_fp8(A, v[j]); acc_fp8(B, v[j + 1]); }
  }
  for (; i + 4 <= cnt; i += 4) {
    unsigned v[4];
#pragma unroll
    for (int j = 0; j < 4; ++j)
      v[j] = *(const unsigned*)(hn8 + (size_t)cp[i + j] * 256 + boff);
    acc_fp8(A, v[0]); acc_fp8(B, v[1]); acc_fp8(A, v[2]); acc_fp8(B, v[3]);
  }
  for (; i < cnt; ++i)
    acc_fp8(A, *(const unsigned*)(hn8 + (size_t)cp[i] * 256 + boff));
  return float4{A.x + B.x, A.y + B.y, A.z + B.z, A.w + B.w};
}

// ---------------- agg1: per-node fp8 output (12500 blocks, R20 form) ----------------
__global__ __launch_bounds__(256) void agg1_kernel(const unsigned char* __restrict__ hn8,
                                                   const float* __restrict__ dinv,
                                                   const int* __restrict__ rowptr,
                                                   const int* __restrict__ csr,
                                                   const float* __restrict__ bias,
                                                   unsigned char* __restrict__ h1p8) {
  int wave = threadIdx.x >> 6, lane = threadIdx.x & 63;
  int node = blockIdx.x * 4 + wave;
  int c0 = lane * 4;
  float4 a = gather_node(hn8, rowptr, csr, node, c0);
  float di = dinv[node];
  float4 b = *(const float4*)(bias + c0);
  float r0 = fmaxf(fmaf(di, a.x, b.x), 0.f);
  float r1 = fmaxf(fmaf(di, a.y, b.y), 0.f);
  float r2 = fmaxf(fmaf(di, a.z, b.z), 0.f);
  float r3 = fmaxf(fmaf(di, a.w, b.w), 0.f);
  int p = __builtin_amdgcn_cvt_pk_fp8_f32(r0, r1, 0, false);
  p     = __builtin_amdgcn_cvt_pk_fp8_f32(r2, r3, p, true);
  *(unsigned*)(h1p8 + (size_t)node * 256 + c0) = (unsigned)p;
}

// ------- agg2: persistent grid-stride, register accumulation (R20, confirmed) -------
__global__ __launch_bounds__(256) void agg2_kernel(const unsigned char* __restrict__ hn8,
                                                   const float* __restrict__ dinv,
                                                   const int* __restrict__ rowptr,
                                                   const int* __restrict__ csr,
                                                   const float* __restrict__ bias,
                                                   float* __restrict__ partials) {
  __shared__ float sm[1024];
  int wave = threadIdx.x >> 6, lane = threadIdx.x & 63;
  int c0 = lane * 4;
  float4 bq = *(const float4*)(bias + c0);
  float s0 = 0.f, s1 = 0.f, s2 = 0.f, s3 = 0.f;
  for (int node = blockIdx.x * 4 + wave; node < NODES; node += AGG2_BLOCKS * 4) {
    float4 a = gather_node(hn8, rowptr, csr, node, c0);
    float di = dinv[node];
    s0 += fmaxf(fmaf(di, a.x, bq.x), 0.f);
    s1 += fmaxf(fmaf(di, a.y, bq.y), 0.f);
    s2 += fmaxf(fmaf(di, a.z, bq.z), 0.f);
    s3 += fmaxf(fmaf(di, a.w, bq.w), 0.f);
  }
  sm[wave * 256 + c0 + 0] = s0;
  sm[wave * 256 + c0 + 1] = s1;
  sm[wave * 256 + c0 + 2] = s2;
  sm[wave * 256 + c0 + 3] = s3;
  __syncthreads();
  int t = threadIdx.x;
  partials[(size_t)blockIdx.x * 256 + t] = sm[t] + sm[256 + t] + sm[512 + t] + sm[768 + t];
}

// ---------------- readout ----------------
__global__ __launch_bounds__(256) void reduce2_kernel(const float* __restrict__ partials,
                                                      float* __restrict__ p2) {
  int t = threadIdx.x, b = blockIdx.x;              // 64 blocks
  float s = 0.f;
  for (int r = b; r < AGG2_BLOCKS; r += RED_BLOCKS) s += partials[(size_t)r * 256 + t];
  p2[b * 256 + t] = s;
}
__global__ __launch_bounds__(256) void final_kernel(const float* __restrict__ p2,
                                                    const float* __restrict__ Wfc,
                                                    const float* __restrict__ bfc,
                                                    float* __restrict__ out) {
  __shared__ float red[256];
  int t = threadIdx.x;
  float s = 0.f;
  for (int b = 0; b < RED_BLOCKS; ++b) s += p2[b * 256 + t];
  float g = s * (1.0f / (float)NODES);
  red[t] = g * Wfc[t];
  __syncthreads();
  for (int off = 128; off > 0; off >>= 1) {
    if (t < off) red[t] += red[t + off];
    __syncthreads();
  }
  if (t == 0) {
    float z = red[0] + bfc[0];
    out[0] = 1.0f / (1.0f + expf(-z));
  }
}

// ---------------- launch ----------------
extern "C" void kernel_launch(void* const* d_in, const int* in_sizes, int n_in,
                              void* d_out, int out_size, void* d_ws, size_t ws_size,
                              hipStream_t stream) {
  (void)in_sizes; (void)n_in; (void)out_size; (void)ws_size;
  const float* x   = (const float*)d_in[0];
  const int*   ei  = (const int*)d_in[1];
  const float* W1  = (const float*)d_in[2];
  const float* b1  = (const float*)d_in[3];
  const float* W2  = (const float*)d_in[4];
  const float* b2  = (const float*)d_in[5];
  const float* Wfc = (const float*)d_in[6];
  const float* bfc = (const float*)d_in[7];
  float* out = (float*)d_out;
  char* ws = (char*)d_ws;

  unsigned char*  hn8  = (unsigned char*)(ws + OFF_HN);
  unsigned char*  h1p8 = (unsigned char*)(ws + OFF_H1P);
  unsigned short* w1t  = (unsigned short*)(ws + OFF_W1T);
  unsigned char*  w2t8 = (unsigned char*)(ws + OFF_W2T8);
  int*   deg    = (int*)(ws + OFF_DEG);
  int*   fill   = (int*)(ws + OFF_FILL);
  int*   rowptr = (int*)(ws + OFF_ROWP);
  int*   csr    = (int*)(ws + OFF_CSR);
  int*   bsum   = (int*)(ws + OFF_BSUM);
  int*   boff   = (int*)(ws + OFF_BOFF);
  float* part   = (float*)(ws + OFF_PART);
  float* p2     = (float*)(ws + OFF_P2);
  float* dinv   = (float*)(ws + OFF_DINV);

  transw_zero_kernel<<<866, 256, 0, stream>>>(W1, W2, w1t, w2t8, (int4*)deg);
  hist_kernel<<<EDGES / 256, 256, 0, stream>>>(ei, deg);
  scan1_kernel<<<NB_SCAN, 256, 0, stream>>>(deg, rowptr, bsum, dinv);
  scan2_kernel<<<1, 256, 0, stream>>>(bsum, boff, rowptr + NODES);
  scan3_kernel<<<NB_SCAN, 256, 0, stream>>>(rowptr, boff);
  fill_kernel<<<EDGES / 256, 256, 0, stream>>>(ei, rowptr, fill, csr);

  gemm1_kernel<<<GEMM_MB256, 512, 0, stream>>>(x, w1t, dinv, hn8);
  agg1_kernel<<<AGG_BLOCKS, 256, 0, stream>>>(hn8, dinv, rowptr, csr, b1, h1p8);
  gemm2_fp8_kernel<<<GEMM_MB256, 512, 0, stream>>>(h1p8, w2t8, dinv, hn8);
  agg2_kernel<<<AGG2_BLOCKS, 256, 0, stream>>>(hn8, dinv, rowptr, csr, b2, part);
  reduce2_kernel<<<RED_BLOCKS, 256, 0, stream>>>(part, p2);
  final_kernel<<<1, 256, 0, stream>>>(p2, Wfc, bfc, out);
}